// Round 9
// baseline (314.648 us; speedup 1.0000x reference)
//
#include <hip/hip_runtime.h>

#define B_ 2
#define S_ 2048
#define D_ 1024
#define H_ 16
#define M_ 4096

typedef unsigned short u16;
typedef unsigned int u32;
typedef short bf8 __attribute__((ext_vector_type(8)));
typedef float f4 __attribute__((ext_vector_type(4)));

#define MFMA16(a, b, c) __builtin_amdgcn_mfma_f32_16x16x32_bf16(a, b, c, 0, 0, 0)

__device__ __forceinline__ u16 f2b(float f) {
  u32 u = __builtin_bit_cast(u32, f);
  u += 0x7fffu + ((u >> 16) & 1);
  return (u16)(u >> 16);
}
__device__ __forceinline__ u32 pack2(float lo, float hi) {
  return (u32)f2b(lo) | ((u32)f2b(hi) << 16);
}
__device__ __forceinline__ float b2f(u16 h) {
  return __builtin_bit_cast(float, (u32)h << 16);
}
__device__ __forceinline__ bf8 g16(const u16* p) { return *(const bf8*)p; }

// Read one MFMA operand fragment from a swizzled LDS tile (row stride 64 bf16).
__device__ __forceinline__ bf8 ldA(const u16* lds, int rowBase, int kc, int lane) {
  int row = rowBase + (lane & 15);
  int c = (kc * 4 + (lane >> 4)) ^ (row & 7);
  return *(const bf8*)(lds + row * 64 + c * 8);
}

// Async-stage 8 rows x 128B into LDS via global_load_lds. LDS dest is linear
// (wave-uniform base + lane*16); XOR swizzle applied to the GLOBAL source addr
// (involution), so LDS lands in the ldA-compatible layout.
__device__ __forceinline__ void stage_async(u16* ldsdst, const u16* __restrict__ gsrc,
                                            int srcStride, int lane) {
  int row = lane >> 3;
  int c16 = (lane & 7) ^ (row & 7);
  const u16* g = gsrc + (size_t)row * srcStride + c16 * 8;
  __builtin_amdgcn_global_load_lds((const __attribute__((address_space(1))) void*)g,
                                   (__attribute__((address_space(3))) void*)ldsdst,
                                   16, 0, 0);
}

#define WAITVM(N)                                          \
  asm volatile("s_waitcnt vmcnt(" #N ")" ::: "memory");    \
  __builtin_amdgcn_sched_barrier(0)
#define BAR()                      \
  __builtin_amdgcn_s_barrier();    \
  __builtin_amdgcn_sched_barrier(0)

// ---------------- f32 -> bf16 flat convert, z selects Q/K/V ----------------
__global__ __launch_bounds__(256) void cvtk3(const float* __restrict__ Q,
                                             const float* __restrict__ K,
                                             const float* __restrict__ V,
                                             u16* __restrict__ Xq,
                                             u16* __restrict__ Xk,
                                             u16* __restrict__ Xv) {
  int z = blockIdx.z;
  const float* in = z == 0 ? Q : z == 1 ? K : V;
  u16* out = z == 0 ? Xq : z == 1 ? Xk : Xv;
  int i = (blockIdx.x * 256 + threadIdx.x) * 8;
  float4 a = *(const float4*)(in + i);
  float4 b = *(const float4*)(in + i + 4);
  uint4 o;
  o.x = pack2(a.x, a.y);
  o.y = pack2(a.z, a.w);
  o.z = pack2(b.x, b.y);
  o.w = pack2(b.z, b.w);
  *(uint4*)(out + i) = o;
}

// ------------- fused weight transpose+convert for Wq/Wk/Wv/Wm -------------
// z in [0,48): Wq/Wk/Wv head z&15 of matrix z>>4 (only y==0 active).
// z == 48  : Wm tile (x, y) of the 1024x1024 matrix.
__global__ __launch_bounds__(256) void tcvtW(const float* __restrict__ Wq,
                                             const float* __restrict__ Wk,
                                             const float* __restrict__ Wv,
                                             const float* __restrict__ Wm,
                                             u16* __restrict__ WT0,
                                             u16* __restrict__ WT1,
                                             u16* __restrict__ WT2,
                                             u16* __restrict__ WT3) {
  int rt = blockIdx.x, ct = blockIdx.y, z = blockIdx.z;
  const float* in;
  u16* out;
  int R, C;
  if (z < 48) {
    if (ct != 0) return;
    int mat = z >> 4, hh = z & 15;
    in = (mat == 0 ? Wq : mat == 1 ? Wk : Wv) + (size_t)hh * 1024 * 64;
    out = (mat == 0 ? WT0 : mat == 1 ? WT1 : WT2) + (size_t)hh * 1024 * 64;
    R = 1024;
    C = 64;
  } else {
    in = Wm;
    out = WT3;
    R = 1024;
    C = 1024;
  }
  __shared__ float tile[64][65];
  int t = threadIdx.x;
  int r = t >> 2, cc = (t & 3) * 16;
#pragma unroll
  for (int j = 0; j < 16; j += 4) {
    float4 v = *(const float4*)(in + (size_t)(rt * 64 + r) * C + ct * 64 + cc + j);
    tile[r][cc + j] = v.x;
    tile[r][cc + j + 1] = v.y;
    tile[r][cc + j + 2] = v.z;
    tile[r][cc + j + 3] = v.w;
  }
  __syncthreads();
  int c = t >> 2;
  u32 buf[8];
#pragma unroll
  for (int j = 0; j < 8; ++j)
    buf[j] = pack2(tile[cc + 2 * j][c], tile[cc + 2 * j + 1][c]);
  uint4* dst = (uint4*)(out + (size_t)(ct * 64 + c) * R + rt * 64 + cc);
  dst[0] = make_uint4(buf[0], buf[1], buf[2], buf[3]);
  dst[1] = make_uint4(buf[4], buf[5], buf[6], buf[7]);
}

// ------------- Q/K/V projection: bf16 A, gload_lds dbuf, 1 barrier/K-step -------------
__global__ __launch_bounds__(256) void proj4(
    const u16* __restrict__ Xq, const u16* __restrict__ Xk,
    const u16* __restrict__ Xv, const u16* __restrict__ WT0,
    const u16* __restrict__ WT1, const u16* __restrict__ WT2,
    const float* __restrict__ bq, const float* __restrict__ bk,
    const float* __restrict__ bv, u16* __restrict__ qp, u16* __restrict__ kp,
    u16* __restrict__ vTp) {
  int mt = blockIdx.x, nt = blockIdx.y, z = blockIdx.z;
  const u16* Ap = z == 0 ? Xq : z == 1 ? Xk : Xv;
  const u16* BT = z == 0 ? WT0 : z == 1 ? WT1 : WT2;
  const float* bias = z == 0 ? bq : z == 1 ? bk : bv;
  float scale = z == 0 ? 0.125f : 1.0f;
  int t = threadIdx.x, lane = t & 63, w = t >> 6;
  int wr = w >> 1, wc = w & 1;
  int quad = lane >> 4, col = lane & 15;
  __shared__ u16 Asm[2][128 * 64], Bsm[2][128 * 64];

#define PSTG(bi, kt)                                                            \
  {                                                                             \
    _Pragma("unroll") for (int cc_ = 0; cc_ < 4; ++cc_) {                       \
      int rb_ = w * 32 + cc_ * 8;                                               \
      stage_async(Asm[bi] + rb_ * 64,                                           \
                  Ap + (size_t)(mt * 128 + rb_) * 1024 + (kt) * 64, 1024, lane);\
      stage_async(Bsm[bi] + rb_ * 64,                                           \
                  BT + (size_t)(nt * 128 + rb_) * 1024 + (kt) * 64, 1024, lane);\
    }                                                                           \
  }

  f4 acc[4][4] = {};
  PSTG(0, 0);
  WAITVM(0);
  BAR();
  for (int kt = 0; kt < 16; ++kt) {
    int bi = kt & 1;
    if (kt < 15) PSTG(bi ^ 1, kt + 1);
#pragma unroll
    for (int kc = 0; kc < 2; ++kc) {
      bf8 a[4], b[4];
#pragma unroll
      for (int fr = 0; fr < 4; ++fr) a[fr] = ldA(Asm[bi], wr * 64 + fr * 16, kc, lane);
#pragma unroll
      for (int nf = 0; nf < 4; ++nf) b[nf] = ldA(Bsm[bi], wc * 64 + nf * 16, kc, lane);
      __builtin_amdgcn_s_setprio(1);
#pragma unroll
      for (int fr = 0; fr < 4; ++fr)
#pragma unroll
        for (int nf = 0; nf < 4; ++nf)
          acc[fr][nf] = MFMA16(a[fr], b[nf], acc[fr][nf]);
      __builtin_amdgcn_s_setprio(0);
    }
    if (kt < 15) {
      WAITVM(0);
      BAR();
    }
  }
#undef PSTG
  if (z < 2) {
    u16* outp = z == 0 ? qp : kp;
#pragma unroll
    for (int fr = 0; fr < 4; ++fr)
#pragma unroll
      for (int nf = 0; nf < 4; ++nf) {
        int n = nt * 128 + wc * 64 + nf * 16 + col;
        int h = n >> 6, d = n & 63;
        float bs = bias[n];
#pragma unroll
        for (int r = 0; r < 4; ++r) {
          int gm = mt * 128 + wr * 64 + fr * 16 + quad * 4 + r;
          int bb = gm >> 11, s = gm & 2047;
          outp[(size_t)((bb * H_ + h) * S_ + s) * 64 + d] =
              f2b((acc[fr][nf][r] + bs) * scale);
        }
      }
  } else {
    // V: write transposed [B*H*64][S] directly (in-lane r-run is s-contiguous)
#pragma unroll
    for (int fr = 0; fr < 4; ++fr)
#pragma unroll
      for (int nf = 0; nf < 4; ++nf) {
        int n = nt * 128 + wc * 64 + nf * 16 + col;
        int h = n >> 6, d = n & 63;
        float bs = bias[n];
        int s0 = mt * 128 + wr * 64 + fr * 16 + quad * 4;
        int bb = s0 >> 11, s = s0 & 2047;
        uint2 u;
        u.x = pack2(acc[fr][nf][0] + bs, acc[fr][nf][1] + bs);
        u.y = pack2(acc[fr][nf][2] + bs, acc[fr][nf][3] + bs);
        *(uint2*)(vTp + (size_t)((bb * H_ + h) * 64 + d) * S_ + s) = u;
      }
  }
}

// ------------- output GEMM: same pipeline, f32 row-major out -------------
__global__ __launch_bounds__(256) void gemmo2(const u16* __restrict__ A,
                                              const u16* __restrict__ BT,
                                              const float* __restrict__ bias,
                                              float* __restrict__ outp) {
  int mt = blockIdx.x, nt = blockIdx.y;
  int t = threadIdx.x, lane = t & 63, w = t >> 6;
  int wr = w >> 1, wc = w & 1;
  int quad = lane >> 4, col = lane & 15;
  __shared__ u16 Asm[2][128 * 64], Bsm[2][128 * 64];

#define PSTG(bi, kt)                                                            \
  {                                                                             \
    _Pragma("unroll") for (int cc_ = 0; cc_ < 4; ++cc_) {                       \
      int rb_ = w * 32 + cc_ * 8;                                               \
      stage_async(Asm[bi] + rb_ * 64,                                           \
                  A + (size_t)(mt * 128 + rb_) * 1024 + (kt) * 64, 1024, lane); \
      stage_async(Bsm[bi] + rb_ * 64,                                           \
                  BT + (size_t)(nt * 128 + rb_) * 1024 + (kt) * 64, 1024, lane);\
    }                                                                           \
  }

  f4 acc[4][4] = {};
  PSTG(0, 0);
  WAITVM(0);
  BAR();
  for (int kt = 0; kt < 16; ++kt) {
    int bi = kt & 1;
    if (kt < 15) PSTG(bi ^ 1, kt + 1);
#pragma unroll
    for (int kc = 0; kc < 2; ++kc) {
      bf8 a[4], b[4];
#pragma unroll
      for (int fr = 0; fr < 4; ++fr) a[fr] = ldA(Asm[bi], wr * 64 + fr * 16, kc, lane);
#pragma unroll
      for (int nf = 0; nf < 4; ++nf) b[nf] = ldA(Bsm[bi], wc * 64 + nf * 16, kc, lane);
      __builtin_amdgcn_s_setprio(1);
#pragma unroll
      for (int fr = 0; fr < 4; ++fr)
#pragma unroll
        for (int nf = 0; nf < 4; ++nf)
          acc[fr][nf] = MFMA16(a[fr], b[nf], acc[fr][nf]);
      __builtin_amdgcn_s_setprio(0);
    }
    if (kt < 15) {
      WAITVM(0);
      BAR();
    }
  }
#undef PSTG
#pragma unroll
  for (int fr = 0; fr < 4; ++fr)
#pragma unroll
    for (int nf = 0; nf < 4; ++nf) {
      int n = nt * 128 + wc * 64 + nf * 16 + col;
      float bs = bias[n];
#pragma unroll
      for (int r = 0; r < 4; ++r) {
        int gm = mt * 128 + wr * 64 + fr * 16 + quad * 4 + r;
        outp[(size_t)gm * 1024 + n] = acc[fr][nf][r] + bs;
      }
    }
}

// ------------- fused attention v8 -------------
// pass 1: 4-slot K ring, TWO tiles per barrier (16 barriers), counted vmcnt(4):
//   iter i computes tiles 2i,2i+1 (retired by the wait), stages 2i+2,2i+3.
// pass 2: attn7's counted-vmcnt pipeline (vmcnt(4): stages retired, stores float).
// s_setprio(1) wraps MFMA clusters (T5; blocks are phase-desynced).
__global__ void attn8(const u16* __restrict__ qp, const u16* __restrict__ kp,
                      const u16* __restrict__ vT, u16* __restrict__ ctxo,
                      float* __restrict__ attw) {
  int bid = blockIdx.x;
  int l = (bid & 7) * 128 + (bid >> 3);
  int qt = l & 31, hb = l >> 5;
  int h = hb & 15, b = hb >> 4;
  int t = threadIdx.x, lane = t & 63, w = t >> 6;
  int quad = lane >> 4, col = lane & 15;

  __shared__ u16 KV[4][64 * 64];  // pass1: 4-slot K ring; pass2: K dbuf=0,1 V dbuf=2,3
  __shared__ u16 Psm[4][16 * 64];

  const u16* kbase = kp + (size_t)(b * H_ + h) * S_ * 64;
  const u16* vbase = vT + (size_t)(b * H_ + h) * 64 * S_;
  const u16* qrow = qp + ((size_t)(b * H_ + h) * S_ + qt * 64 + w * 16) * 64;
  int r16 = (lane & 15) * 64;
  int c0 = (lane >> 4) * 8, c1 = c0 + 32;
  bf8 qf0 = g16(qrow + r16 + c0);
  bf8 qf1 = g16(qrow + r16 + c1);

#define SLOT(i) (KV[0] + (size_t)((i) & 3) * 4096)
#define SGT(slot, kt)                                                             \
  {                                                                               \
    u16* s_ = (slot);                                                             \
    const u16* g_ = kbase + (size_t)((kt) & 31) * 4096;                           \
    stage_async(s_ + w * 1024, g_ + w * 16 * 64, 64, lane);                       \
    stage_async(s_ + w * 1024 + 512, g_ + (w * 16 + 8) * 64, 64, lane);           \
  }
#define SGV(bi, kt)                                                               \
  {                                                                               \
    u16* s_ = KV[2 + (bi)];                                                       \
    stage_async(s_ + w * 1024, vbase + (size_t)(w * 16) * S_ + (kt) * 64, S_,     \
                lane);                                                            \
    stage_async(s_ + w * 1024 + 512,                                              \
                vbase + (size_t)(w * 16 + 8) * S_ + (kt) * 64, S_, lane);         \
  }
#define QKT(Kc, sc)                                                               \
  {                                                                               \
    _Pragma("unroll") for (int fr = 0; fr < 4; ++fr) {                            \
      bf8 k0 = ldA(Kc, fr * 16, 0, lane);                                         \
      bf8 k1 = ldA(Kc, fr * 16, 1, lane);                                         \
      __builtin_amdgcn_s_setprio(1);                                              \
      sc[fr] = MFMA16(k0, qf0, sc[fr]);                                           \
      sc[fr] = MFMA16(k1, qf1, sc[fr]);                                           \
      __builtin_amdgcn_s_setprio(0);                                              \
    }                                                                             \
  }

  // ---- pass 1: row sums of exp(S); 2 tiles per barrier, 2 tiles in flight ----
  float lsum = 0.f;
  SGT(SLOT(0), 0);
  SGT(SLOT(1), 1);
  WAITVM(0);
  BAR();
  for (int i = 0; i < 16; ++i) {
    int kt = 2 * i;
    SGT(SLOT(kt + 2), kt + 2);  // wraps at i=15: stages K t0,t1 for pass 2
    SGT(SLOT(kt + 3), kt + 3);
    WAITVM(4);  // retire tiles kt,kt+1 (issued one full iteration ago)
    BAR();
#pragma unroll
    for (int half = 0; half < 2; ++half) {
      const u16* Kc = SLOT(kt + half);
      f4 sc[4] = {};
      QKT(Kc, sc);
      float s = 0.f;
#pragma unroll
      for (int fr = 0; fr < 4; ++fr)
#pragma unroll
        for (int r = 0; r < 4; ++r) s += __expf(sc[fr][r]);
      lsum += s;
    }
  }
  lsum += __shfl_xor(lsum, 16);
  lsum += __shfl_xor(lsum, 32);
  float linv = 1.f / lsum;

  // ---- pass 2: recompute S, write normalized P, accumulate ctx^T ----
  // K t0/t1 already in KV[0]/KV[1] from pass 1's wrap stages.
  BAR();  // all waves done reading the ring before V staging overwrites slots 2,3
  SGV(0, 0);
  WAITVM(0);
  BAR();
  f4 ctxa[4] = {};
  u16* Pw = Psm[w];
  size_t awrow = ((size_t)(b * S_ + qt * 64 + w * 16) * H_ + h) * S_;
  for (int kt = 0; kt < 32; ++kt) {
    SGT(SLOT((kt + 1) & 1), kt + 1);
    SGV((kt + 1) & 1, (kt + 1) & 31);
    const u16* Kc = SLOT(kt & 1);
    const u16* Vc = KV[2 + (kt & 1)];
    f4 sc[4] = {};
    QKT(Kc, sc);
    // P strip [16 q][64 key] bf16, swizzled; lane writes q=col, keys fr*16+quad*4+r
#pragma unroll
    for (int fr = 0; fr < 4; ++fr) {
      float p0 = __expf(sc[fr][0]) * linv;
      float p1 = __expf(sc[fr][1]) * linv;
      float p2 = __expf(sc[fr][2]) * linv;
      float p3 = __expf(sc[fr][3]) * linv;
      int bo = col * 128 + ((fr * 32 + quad * 8) ^ ((col & 7) << 4));
      uint2 u;
      u.x = pack2(p0, p1);
      u.y = pack2(p2, p3);
      *(uint2*)((char*)Pw + bo) = u;
    }
    // attw f32 stores (4/lane), issued early; they float across the barrier
#pragma unroll
    for (int it = 0; it < 2; ++it) {
      int row = (lane >> 3) + 8 * it;
      int cc = lane & 7;
      int bo = row * 128 + ((cc ^ (row & 7)) << 4);
      bf8 pv = *(const bf8*)((const char*)Pw + bo);
      float* dst = attw + awrow + (size_t)row * (H_ * S_) + kt * 64 + cc * 8;
      float4 o0, o1;
      o0.x = b2f((u16)pv[0]);
      o0.y = b2f((u16)pv[1]);
      o0.z = b2f((u16)pv[2]);
      o0.w = b2f((u16)pv[3]);
      o1.x = b2f((u16)pv[4]);
      o1.y = b2f((u16)pv[5]);
      o1.z = b2f((u16)pv[6]);
      o1.w = b2f((u16)pv[7]);
      *(float4*)dst = o0;
      *((float4*)dst + 1) = o1;
    }
    // PV: ctx^T[dv][q] += V^T[dv][key] * P[q][key]
    bf8 pf0 = ldA(Pw, 0, 0, lane);
    bf8 pf1 = ldA(Pw, 0, 1, lane);
#pragma unroll
    for (int fr = 0; fr < 4; ++fr) {
      bf8 v0 = ldA(Vc, fr * 16, 0, lane);
      bf8 v1 = ldA(Vc, fr * 16, 1, lane);
      __builtin_amdgcn_s_setprio(1);
      ctxa[fr] = MFMA16(v0, pf0, ctxa[fr]);
      ctxa[fr] = MFMA16(v1, pf1, ctxa[fr]);
      __builtin_amdgcn_s_setprio(0);
    }
    // retire prior stores + this iter's 4 stages; this iter's 4 stores float
    WAITVM(4);
    BAR();
  }
  // ctx epilogue: lane holds q=col, dv = fr*16 + quad*4 + r
  int qg = qt * 64 + w * 16 + col;
  size_t cb = ((size_t)(b * S_ + qg) * H_ + h) * 64;
#pragma unroll
  for (int fr = 0; fr < 4; ++fr) {
    uint2 u;
    u.x = pack2(ctxa[fr][0], ctxa[fr][1]);
    u.y = pack2(ctxa[fr][2], ctxa[fr][3]);
    *(uint2*)(ctxo + cb + fr * 16 + quad * 4) = u;
  }
#undef SLOT
#undef SGT
#undef SGV
#undef QKT
}

extern "C" void kernel_launch(void* const* d_in, const int* in_sizes, int n_in,
                              void* d_out, int out_size, void* d_ws, size_t ws_size,
                              hipStream_t stream) {
  const float* Q = (const float*)d_in[0];
  const float* K = (const float*)d_in[1];
  const float* V = (const float*)d_in[2];
  const float* Wq = (const float*)d_in[3];
  const float* bq = (const float*)d_in[4];
  const float* Wk = (const float*)d_in[5];
  const float* bk = (const float*)d_in[6];
  const float* Wv = (const float*)d_in[7];
  const float* bv = (const float*)d_in[8];
  const float* Wm = (const float*)d_in[9];
  const float* bm = (const float*)d_in[10];
  float* out0 = (float*)d_out;
  float* out1 = out0 + (size_t)M_ * D_;
  (void)in_sizes; (void)n_in; (void)out_size; (void)ws_size;

  u16* WT0 = (u16*)d_ws;            // 1M elems each
  u16* WT1 = WT0 + 1048576;
  u16* WT2 = WT1 + 1048576;
  u16* WT3 = WT2 + 1048576;
  u16* qp = WT3 + 1048576;          // 4M elems each
  u16* kp = qp + 4194304;
  u16* vTp = kp + 4194304;
  u16* ctx = vTp + 4194304;         // doubles as Xq (dead before attn writes ctx)
  u16* Xk = ctx + 4194304;
  u16* Xv = Xk + 4194304;           // total 28M u16 = 56 MB

  cvtk3<<<dim3(2048, 1, 3), 256, 0, stream>>>(Q, K, V, ctx, Xk, Xv);
  tcvtW<<<dim3(16, 16, 49), 256, 0, stream>>>(Wq, Wk, Wv, Wm, WT0, WT1, WT2, WT3);
  proj4<<<dim3(32, 8, 3), 256, 0, stream>>>(ctx, Xk, Xv, WT0, WT1, WT2, bq, bk,
                                            bv, qp, kp, vTp);
  attn8<<<1024, 256, 0, stream>>>(qp, kp, vTp, ctx, out1);
  gemmo2<<<dim3(32, 8), 256, 0, stream>>>(ctx, WT3, bm, out0);
}

// Round 10
// 287.852 us; speedup vs baseline: 1.0931x; 1.0931x over previous
//
#include <hip/hip_runtime.h>

#define B_ 2
#define S_ 2048
#define D_ 1024
#define H_ 16
#define M_ 4096

typedef unsigned short u16;
typedef unsigned int u32;
typedef short bf8 __attribute__((ext_vector_type(8)));
typedef float f4 __attribute__((ext_vector_type(4)));

#define MFMA16(a, b, c) __builtin_amdgcn_mfma_f32_16x16x32_bf16(a, b, c, 0, 0, 0)

__device__ __forceinline__ u16 f2b(float f) {
  u32 u = __builtin_bit_cast(u32, f);
  u += 0x7fffu + ((u >> 16) & 1);
  return (u16)(u >> 16);
}
__device__ __forceinline__ u32 pack2(float lo, float hi) {
  return (u32)f2b(lo) | ((u32)f2b(hi) << 16);
}
__device__ __forceinline__ float b2f(u16 h) {
  return __builtin_bit_cast(float, (u32)h << 16);
}
__device__ __forceinline__ bf8 g16(const u16* p) { return *(const bf8*)p; }

// Read one MFMA operand fragment from a swizzled LDS tile (row stride 64 bf16).
__device__ __forceinline__ bf8 ldA(const u16* lds, int rowBase, int kc, int lane) {
  int row = rowBase + (lane & 15);
  int c = (kc * 4 + (lane >> 4)) ^ (row & 7);
  return *(const bf8*)(lds + row * 64 + c * 8);
}

// Async-stage 8 rows x 128B into LDS via global_load_lds. LDS dest is linear
// (wave-uniform base + lane*16); XOR swizzle applied to the GLOBAL source addr
// (involution), so LDS lands in the ldA-compatible layout.
__device__ __forceinline__ void stage_async(u16* ldsdst, const u16* __restrict__ gsrc,
                                            int srcStride, int lane) {
  int row = lane >> 3;
  int c16 = (lane & 7) ^ (row & 7);
  const u16* g = gsrc + (size_t)row * srcStride + c16 * 8;
  __builtin_amdgcn_global_load_lds((const __attribute__((address_space(1))) void*)g,
                                   (__attribute__((address_space(3))) void*)ldsdst,
                                   16, 0, 0);
}

#define WAITVM(N)                                          \
  asm volatile("s_waitcnt vmcnt(" #N ")" ::: "memory");    \
  __builtin_amdgcn_sched_barrier(0)
#define BAR()                      \
  __builtin_amdgcn_s_barrier();    \
  __builtin_amdgcn_sched_barrier(0)

// ---------------- f32 -> bf16 flat convert, z selects Q/K/V ----------------
__global__ __launch_bounds__(256) void cvtk3(const float* __restrict__ Q,
                                             const float* __restrict__ K,
                                             const float* __restrict__ V,
                                             u16* __restrict__ Xq,
                                             u16* __restrict__ Xk,
                                             u16* __restrict__ Xv) {
  int z = blockIdx.z;
  const float* in = z == 0 ? Q : z == 1 ? K : V;
  u16* out = z == 0 ? Xq : z == 1 ? Xk : Xv;
  int i = (blockIdx.x * 256 + threadIdx.x) * 8;
  float4 a = *(const float4*)(in + i);
  float4 b = *(const float4*)(in + i + 4);
  uint4 o;
  o.x = pack2(a.x, a.y);
  o.y = pack2(a.z, a.w);
  o.z = pack2(b.x, b.y);
  o.w = pack2(b.z, b.w);
  *(uint4*)(out + i) = o;
}

// ------------- fused weight transpose+convert for Wq/Wk/Wv/Wm -------------
// z in [0,48): Wq/Wk/Wv head z&15 of matrix z>>4 (only y==0 active).
// z == 48  : Wm tile (x, y) of the 1024x1024 matrix.
__global__ __launch_bounds__(256) void tcvtW(const float* __restrict__ Wq,
                                             const float* __restrict__ Wk,
                                             const float* __restrict__ Wv,
                                             const float* __restrict__ Wm,
                                             u16* __restrict__ WT0,
                                             u16* __restrict__ WT1,
                                             u16* __restrict__ WT2,
                                             u16* __restrict__ WT3) {
  int rt = blockIdx.x, ct = blockIdx.y, z = blockIdx.z;
  const float* in;
  u16* out;
  int R, C;
  if (z < 48) {
    if (ct != 0) return;
    int mat = z >> 4, hh = z & 15;
    in = (mat == 0 ? Wq : mat == 1 ? Wk : Wv) + (size_t)hh * 1024 * 64;
    out = (mat == 0 ? WT0 : mat == 1 ? WT1 : WT2) + (size_t)hh * 1024 * 64;
    R = 1024;
    C = 64;
  } else {
    in = Wm;
    out = WT3;
    R = 1024;
    C = 1024;
  }
  __shared__ float tile[64][65];
  int t = threadIdx.x;
  int r = t >> 2, cc = (t & 3) * 16;
#pragma unroll
  for (int j = 0; j < 16; j += 4) {
    float4 v = *(const float4*)(in + (size_t)(rt * 64 + r) * C + ct * 64 + cc + j);
    tile[r][cc + j] = v.x;
    tile[r][cc + j + 1] = v.y;
    tile[r][cc + j + 2] = v.z;
    tile[r][cc + j + 3] = v.w;
  }
  __syncthreads();
  int c = t >> 2;
  u32 buf[8];
#pragma unroll
  for (int j = 0; j < 8; ++j)
    buf[j] = pack2(tile[cc + 2 * j][c], tile[cc + 2 * j + 1][c]);
  uint4* dst = (uint4*)(out + (size_t)(ct * 64 + c) * R + rt * 64 + cc);
  dst[0] = make_uint4(buf[0], buf[1], buf[2], buf[3]);
  dst[1] = make_uint4(buf[4], buf[5], buf[6], buf[7]);
}

// ------------- Q/K/V projection: bf16 A, gload_lds dbuf, 1 barrier/K-step -------------
__global__ __launch_bounds__(256) void proj4(
    const u16* __restrict__ Xq, const u16* __restrict__ Xk,
    const u16* __restrict__ Xv, const u16* __restrict__ WT0,
    const u16* __restrict__ WT1, const u16* __restrict__ WT2,
    const float* __restrict__ bq, const float* __restrict__ bk,
    const float* __restrict__ bv, u16* __restrict__ qp, u16* __restrict__ kp,
    u16* __restrict__ vTp) {
  int mt = blockIdx.x, nt = blockIdx.y, z = blockIdx.z;
  const u16* Ap = z == 0 ? Xq : z == 1 ? Xk : Xv;
  const u16* BT = z == 0 ? WT0 : z == 1 ? WT1 : WT2;
  const float* bias = z == 0 ? bq : z == 1 ? bk : bv;
  float scale = z == 0 ? 0.125f : 1.0f;
  int t = threadIdx.x, lane = t & 63, w = t >> 6;
  int wr = w >> 1, wc = w & 1;
  int quad = lane >> 4, col = lane & 15;
  __shared__ u16 Asm[2][128 * 64], Bsm[2][128 * 64];

#define PSTG(bi, kt)                                                            \
  {                                                                             \
    _Pragma("unroll") for (int cc_ = 0; cc_ < 4; ++cc_) {                       \
      int rb_ = w * 32 + cc_ * 8;                                               \
      stage_async(Asm[bi] + rb_ * 64,                                           \
                  Ap + (size_t)(mt * 128 + rb_) * 1024 + (kt) * 64, 1024, lane);\
      stage_async(Bsm[bi] + rb_ * 64,                                           \
                  BT + (size_t)(nt * 128 + rb_) * 1024 + (kt) * 64, 1024, lane);\
    }                                                                           \
  }

  f4 acc[4][4] = {};
  PSTG(0, 0);
  WAITVM(0);
  BAR();
  for (int kt = 0; kt < 16; ++kt) {
    int bi = kt & 1;
    if (kt < 15) PSTG(bi ^ 1, kt + 1);
#pragma unroll
    for (int kc = 0; kc < 2; ++kc) {
      bf8 a[4], b[4];
#pragma unroll
      for (int fr = 0; fr < 4; ++fr) a[fr] = ldA(Asm[bi], wr * 64 + fr * 16, kc, lane);
#pragma unroll
      for (int nf = 0; nf < 4; ++nf) b[nf] = ldA(Bsm[bi], wc * 64 + nf * 16, kc, lane);
#pragma unroll
      for (int fr = 0; fr < 4; ++fr)
#pragma unroll
        for (int nf = 0; nf < 4; ++nf)
          acc[fr][nf] = MFMA16(a[fr], b[nf], acc[fr][nf]);
    }
    if (kt < 15) {
      WAITVM(0);
      BAR();
    }
  }
#undef PSTG
  if (z < 2) {
    u16* outp = z == 0 ? qp : kp;
#pragma unroll
    for (int fr = 0; fr < 4; ++fr)
#pragma unroll
      for (int nf = 0; nf < 4; ++nf) {
        int n = nt * 128 + wc * 64 + nf * 16 + col;
        int h = n >> 6, d = n & 63;
        float bs = bias[n];
#pragma unroll
        for (int r = 0; r < 4; ++r) {
          int gm = mt * 128 + wr * 64 + fr * 16 + quad * 4 + r;
          int bb = gm >> 11, s = gm & 2047;
          outp[(size_t)((bb * H_ + h) * S_ + s) * 64 + d] =
              f2b((acc[fr][nf][r] + bs) * scale);
        }
      }
  } else {
    // V: write transposed [B*H*64][S] directly (in-lane r-run is s-contiguous)
#pragma unroll
    for (int fr = 0; fr < 4; ++fr)
#pragma unroll
      for (int nf = 0; nf < 4; ++nf) {
        int n = nt * 128 + wc * 64 + nf * 16 + col;
        int h = n >> 6, d = n & 63;
        float bs = bias[n];
        int s0 = mt * 128 + wr * 64 + fr * 16 + quad * 4;
        int bb = s0 >> 11, s = s0 & 2047;
        uint2 u;
        u.x = pack2(acc[fr][nf][0] + bs, acc[fr][nf][1] + bs);
        u.y = pack2(acc[fr][nf][2] + bs, acc[fr][nf][3] + bs);
        *(uint2*)(vTp + (size_t)((bb * H_ + h) * 64 + d) * S_ + s) = u;
      }
  }
}

// ------------- output GEMM: same pipeline, f32 row-major out -------------
__global__ __launch_bounds__(256) void gemmo2(const u16* __restrict__ A,
                                              const u16* __restrict__ BT,
                                              const float* __restrict__ bias,
                                              float* __restrict__ outp) {
  int mt = blockIdx.x, nt = blockIdx.y;
  int t = threadIdx.x, lane = t & 63, w = t >> 6;
  int wr = w >> 1, wc = w & 1;
  int quad = lane >> 4, col = lane & 15;
  __shared__ u16 Asm[2][128 * 64], Bsm[2][128 * 64];

#define PSTG(bi, kt)                                                            \
  {                                                                             \
    _Pragma("unroll") for (int cc_ = 0; cc_ < 4; ++cc_) {                       \
      int rb_ = w * 32 + cc_ * 8;                                               \
      stage_async(Asm[bi] + rb_ * 64,                                           \
                  A + (size_t)(mt * 128 + rb_) * 1024 + (kt) * 64, 1024, lane); \
      stage_async(Bsm[bi] + rb_ * 64,                                           \
                  BT + (size_t)(nt * 128 + rb_) * 1024 + (kt) * 64, 1024, lane);\
    }                                                                           \
  }

  f4 acc[4][4] = {};
  PSTG(0, 0);
  WAITVM(0);
  BAR();
  for (int kt = 0; kt < 16; ++kt) {
    int bi = kt & 1;
    if (kt < 15) PSTG(bi ^ 1, kt + 1);
#pragma unroll
    for (int kc = 0; kc < 2; ++kc) {
      bf8 a[4], b[4];
#pragma unroll
      for (int fr = 0; fr < 4; ++fr) a[fr] = ldA(Asm[bi], wr * 64 + fr * 16, kc, lane);
#pragma unroll
      for (int nf = 0; nf < 4; ++nf) b[nf] = ldA(Bsm[bi], wc * 64 + nf * 16, kc, lane);
#pragma unroll
      for (int fr = 0; fr < 4; ++fr)
#pragma unroll
        for (int nf = 0; nf < 4; ++nf)
          acc[fr][nf] = MFMA16(a[fr], b[nf], acc[fr][nf]);
    }
    if (kt < 15) {
      WAITVM(0);
      BAR();
    }
  }
#undef PSTG
#pragma unroll
  for (int fr = 0; fr < 4; ++fr)
#pragma unroll
    for (int nf = 0; nf < 4; ++nf) {
      int n = nt * 128 + wc * 64 + nf * 16 + col;
      float bs = bias[n];
#pragma unroll
      for (int r = 0; r < 4; ++r) {
        int gm = mt * 128 + wr * 64 + fr * 16 + quad * 4 + r;
        outp[(size_t)gm * 1024 + n] = acc[fr][nf][r] + bs;
      }
    }
}

// ------------- fused attention v7 (R8 winner, reverted verbatim) -------------
// pass 1: 4-slot K ring, 1 tile/barrier, staged 2 tiles ahead, vmcnt(4); the slot
// being overwritten was read 2 iterations (2 barriers) ago -> race-free.
// pass 2: counted-vmcnt pipeline; barrier sits AFTER compute, before the next
// overwrite -> race-free; vmcnt(4) retires stages, floats this iter's stores.
__global__ void attn7(const u16* __restrict__ qp, const u16* __restrict__ kp,
                      const u16* __restrict__ vT, u16* __restrict__ ctxo,
                      float* __restrict__ attw) {
  int bid = blockIdx.x;
  int l = (bid & 7) * 128 + (bid >> 3);
  int qt = l & 31, hb = l >> 5;
  int h = hb & 15, b = hb >> 4;
  int t = threadIdx.x, lane = t & 63, w = t >> 6;
  int quad = lane >> 4, col = lane & 15;

  __shared__ u16 KV[4][64 * 64];  // pass1: 4-slot K ring; pass2: K dbuf=0,1 V dbuf=2,3
  __shared__ u16 Psm[4][16 * 64];

  const u16* kbase = kp + (size_t)(b * H_ + h) * S_ * 64;
  const u16* vbase = vT + (size_t)(b * H_ + h) * 64 * S_;
  const u16* qrow = qp + ((size_t)(b * H_ + h) * S_ + qt * 64 + w * 16) * 64;
  int r16 = (lane & 15) * 64;
  int c0 = (lane >> 4) * 8, c1 = c0 + 32;
  bf8 qf0 = g16(qrow + r16 + c0);
  bf8 qf1 = g16(qrow + r16 + c1);

#define SLOT(i) (KV[0] + (size_t)((i) & 3) * 4096)
#define SGT(slot, kt)                                                             \
  {                                                                               \
    u16* s_ = (slot);                                                             \
    const u16* g_ = kbase + (size_t)((kt) & 31) * 4096;                           \
    stage_async(s_ + w * 1024, g_ + w * 16 * 64, 64, lane);                       \
    stage_async(s_ + w * 1024 + 512, g_ + (w * 16 + 8) * 64, 64, lane);           \
  }
#define SGV(bi, kt)                                                               \
  {                                                                               \
    u16* s_ = KV[2 + (bi)];                                                       \
    stage_async(s_ + w * 1024, vbase + (size_t)(w * 16) * S_ + (kt) * 64, S_,     \
                lane);                                                            \
    stage_async(s_ + w * 1024 + 512,                                              \
                vbase + (size_t)(w * 16 + 8) * S_ + (kt) * 64, S_, lane);         \
  }

  // ---- pass 1: row sums of exp(S); ring pipeline, 2 tiles in flight ----
  SGT(SLOT(0), 0);
  SGT(SLOT(1), 1);
  WAITVM(2);  // qf loads + tile-0 stages retired (tile-1 still in flight)
  BAR();
  float lsum = 0.f;
  for (int kt = 0; kt < 32; ++kt) {
    SGT(SLOT(kt + 2), kt + 2);  // wraps: kt=30,31 pre-stage K t0,t1 for pass 2
    WAITVM(4);                  // retire tile kt (staged 2 compute-phases ago)
    BAR();
    const u16* Kc = SLOT(kt);
    f4 sc[4] = {};
#pragma unroll
    for (int fr = 0; fr < 4; ++fr) {
      bf8 k0 = ldA(Kc, fr * 16, 0, lane);
      bf8 k1 = ldA(Kc, fr * 16, 1, lane);
      sc[fr] = MFMA16(k0, qf0, sc[fr]);
      sc[fr] = MFMA16(k1, qf1, sc[fr]);
    }
    float s = 0.f;
#pragma unroll
    for (int fr = 0; fr < 4; ++fr)
#pragma unroll
      for (int r = 0; r < 4; ++r) s += __expf(sc[fr][r]);
    lsum += s;
  }
  lsum += __shfl_xor(lsum, 16);
  lsum += __shfl_xor(lsum, 32);
  float linv = 1.f / lsum;

  // ---- pass 2: recompute S, write normalized P, accumulate ctx^T ----
  // K t0/t1 already in KV[0]/KV[1] from pass 1's wrap stages.
  BAR();  // all waves done reading the ring before V staging overwrites slots 2,3
  SGV(0, 0);
  WAITVM(0);
  BAR();
  f4 ctxa[4] = {};
  u16* Pw = Psm[w];
  size_t awrow = ((size_t)(b * S_ + qt * 64 + w * 16) * H_ + h) * S_;
  for (int kt = 0; kt < 32; ++kt) {
    SGT(SLOT((kt + 1) & 1), kt + 1);
    SGV((kt + 1) & 1, (kt + 1) & 31);
    const u16* Kc = SLOT(kt & 1);
    const u16* Vc = KV[2 + (kt & 1)];
    f4 sc[4] = {};
#pragma unroll
    for (int fr = 0; fr < 4; ++fr) {
      bf8 k0 = ldA(Kc, fr * 16, 0, lane);
      bf8 k1 = ldA(Kc, fr * 16, 1, lane);
      sc[fr] = MFMA16(k0, qf0, sc[fr]);
      sc[fr] = MFMA16(k1, qf1, sc[fr]);
    }
    // P strip [16 q][64 key] bf16, swizzled; lane writes q=col, keys fr*16+quad*4+r
#pragma unroll
    for (int fr = 0; fr < 4; ++fr) {
      float p0 = __expf(sc[fr][0]) * linv;
      float p1 = __expf(sc[fr][1]) * linv;
      float p2 = __expf(sc[fr][2]) * linv;
      float p3 = __expf(sc[fr][3]) * linv;
      int bo = col * 128 + ((fr * 32 + quad * 8) ^ ((col & 7) << 4));
      uint2 u;
      u.x = pack2(p0, p1);
      u.y = pack2(p2, p3);
      *(uint2*)((char*)Pw + bo) = u;
    }
    // attw f32 stores (4/lane), issued early; they float across the barrier
#pragma unroll
    for (int it = 0; it < 2; ++it) {
      int row = (lane >> 3) + 8 * it;
      int cc = lane & 7;
      int bo = row * 128 + ((cc ^ (row & 7)) << 4);
      bf8 pv = *(const bf8*)((const char*)Pw + bo);
      float* dst = attw + awrow + (size_t)row * (H_ * S_) + kt * 64 + cc * 8;
      float4 o0, o1;
      o0.x = b2f((u16)pv[0]);
      o0.y = b2f((u16)pv[1]);
      o0.z = b2f((u16)pv[2]);
      o0.w = b2f((u16)pv[3]);
      o1.x = b2f((u16)pv[4]);
      o1.y = b2f((u16)pv[5]);
      o1.z = b2f((u16)pv[6]);
      o1.w = b2f((u16)pv[7]);
      *(float4*)dst = o0;
      *((float4*)dst + 1) = o1;
    }
    // PV: ctx^T[dv][q] += V^T[dv][key] * P[q][key]
    bf8 pf0 = ldA(Pw, 0, 0, lane);
    bf8 pf1 = ldA(Pw, 0, 1, lane);
#pragma unroll
    for (int fr = 0; fr < 4; ++fr) {
      bf8 v0 = ldA(Vc, fr * 16, 0, lane);
      bf8 v1 = ldA(Vc, fr * 16, 1, lane);
      ctxa[fr] = MFMA16(v0, pf0, ctxa[fr]);
      ctxa[fr] = MFMA16(v1, pf1, ctxa[fr]);
    }
    // retire prior stores + this iter's 4 stages; this iter's 4 stores float
    WAITVM(4);
    BAR();
  }
  // ctx epilogue: lane holds q=col, dv = fr*16 + quad*4 + r
  int qg = qt * 64 + w * 16 + col;
  size_t cb = ((size_t)(b * S_ + qg) * H_ + h) * 64;
#pragma unroll
  for (int fr = 0; fr < 4; ++fr) {
    uint2 u;
    u.x = pack2(ctxa[fr][0], ctxa[fr][1]);
    u.y = pack2(ctxa[fr][2], ctxa[fr][3]);
    *(uint2*)(ctxo + cb + fr * 16 + quad * 4) = u;
  }
#undef SLOT
#undef SGT
#undef SGV
}

extern "C" void kernel_launch(void* const* d_in, const int* in_sizes, int n_in,
                              void* d_out, int out_size, void* d_ws, size_t ws_size,
                              hipStream_t stream) {
  const float* Q = (const float*)d_in[0];
  const float* K = (const float*)d_in[1];
  const float* V = (const float*)d_in[2];
  const float* Wq = (const float*)d_in[3];
  const float* bq = (const float*)d_in[4];
  const float* Wk = (const float*)d_in[5];
  const float* bk = (const float*)d_in[6];
  const float* Wv = (const float*)d_in[7];
  const float* bv = (const float*)d_in[8];
  const float* Wm = (const float*)d_in[9];
  const float* bm = (const float*)d_in[10];
  float* out0 = (float*)d_out;
  float* out1 = out0 + (size_t)M_ * D_;
  (void)in_sizes; (void)n_in; (void)out_size; (void)ws_size;

  u16* WT0 = (u16*)d_ws;            // 1M elems each
  u16* WT1 = WT0 + 1048576;
  u16* WT2 = WT1 + 1048576;
  u16* WT3 = WT2 + 1048576;
  u16* qp = WT3 + 1048576;          // 4M elems each
  u16* kp = qp + 4194304;
  u16* vTp = kp + 4194304;
  u16* ctx = vTp + 4194304;         // doubles as Xq (dead before attn writes ctx)
  u16* Xk = ctx + 4194304;
  u16* Xv = Xk + 4194304;           // total 28M u16 = 56 MB

  cvtk3<<<dim3(2048, 1, 3), 256, 0, stream>>>(Q, K, V, ctx, Xk, Xv);
  tcvtW<<<dim3(16, 16, 49), 256, 0, stream>>>(Wq, Wk, Wv, Wm, WT0, WT1, WT2, WT3);
  proj4<<<dim3(32, 8, 3), 256, 0, stream>>>(ctx, Xk, Xv, WT0, WT1, WT2, bq, bk,
                                            bv, qp, kp, vTp);
  attn7<<<1024, 256, 0, stream>>>(qp, kp, vTp, ctx, out1);
  gemmo2<<<dim3(32, 8), 256, 0, stream>>>(ctx, WT3, bm, out0);
}

// Round 11
// 283.082 us; speedup vs baseline: 1.1115x; 1.0169x over previous
//
#include <hip/hip_runtime.h>

#define B_ 2
#define S_ 2048
#define D_ 1024
#define H_ 16
#define M_ 4096

typedef unsigned short u16;
typedef unsigned int u32;
typedef short bf8 __attribute__((ext_vector_type(8)));
typedef float f4 __attribute__((ext_vector_type(4)));

#define MFMA16(a, b, c) __builtin_amdgcn_mfma_f32_16x16x32_bf16(a, b, c, 0, 0, 0)

__device__ __forceinline__ u16 f2b(float f) {
  u32 u = __builtin_bit_cast(u32, f);
  u += 0x7fffu + ((u >> 16) & 1);
  return (u16)(u >> 16);
}
__device__ __forceinline__ u32 pack2(float lo, float hi) {
  return (u32)f2b(lo) | ((u32)f2b(hi) << 16);
}
__device__ __forceinline__ float b2f(u16 h) {
  return __builtin_bit_cast(float, (u32)h << 16);
}
__device__ __forceinline__ bf8 g16(const u16* p) { return *(const bf8*)p; }

// Read one MFMA operand fragment from a swizzled LDS tile (row stride 64 bf16).
__device__ __forceinline__ bf8 ldA(const u16* lds, int rowBase, int kc, int lane) {
  int row = rowBase + (lane & 15);
  int c = (kc * 4 + (lane >> 4)) ^ (row & 7);
  return *(const bf8*)(lds + row * 64 + c * 8);
}

// Async-stage 8 rows x 128B into LDS via global_load_lds. LDS dest is linear
// (wave-uniform base + lane*16); XOR swizzle applied to the GLOBAL source addr
// (involution), so LDS lands in the ldA-compatible layout.
__device__ __forceinline__ void stage_async(u16* ldsdst, const u16* __restrict__ gsrc,
                                            int srcStride, int lane) {
  int row = lane >> 3;
  int c16 = (lane & 7) ^ (row & 7);
  const u16* g = gsrc + (size_t)row * srcStride + c16 * 8;
  __builtin_amdgcn_global_load_lds((const __attribute__((address_space(1))) void*)g,
                                   (__attribute__((address_space(3))) void*)ldsdst,
                                   16, 0, 0);
}

#define WAITVM(N)                                          \
  asm volatile("s_waitcnt vmcnt(" #N ")" ::: "memory");    \
  __builtin_amdgcn_sched_barrier(0)
#define BAR()                      \
  __builtin_amdgcn_s_barrier();    \
  __builtin_amdgcn_sched_barrier(0)

// ------------- prep: Q/K/V f32->bf16 flat convert + all weight transposes -------------
// bid < 6144          : flat convert; z = bid/2048 selects Q/K/V, 2048 elems*... per block
// bid in [6144, 6912) : Wq/Wk/Wv head transpose (wid>>4 = mat*16+... wid = bid-6144,
//                       mat = wid/256? no: z'=wid>>4 in [0,48), rt = wid&15)
// bid in [6912, 7168) : Wm 64x64 tile (idx = bid-6912, rt = idx&15, ct = idx>>4)
__global__ __launch_bounds__(256) void prep(
    const float* __restrict__ Q, const float* __restrict__ K,
    const float* __restrict__ V, const float* __restrict__ Wq,
    const float* __restrict__ Wk, const float* __restrict__ Wv,
    const float* __restrict__ Wm, u16* __restrict__ Xq, u16* __restrict__ Xk,
    u16* __restrict__ Xv, u16* __restrict__ WT0, u16* __restrict__ WT1,
    u16* __restrict__ WT2, u16* __restrict__ WT3) {
  int bid = blockIdx.x;
  int t = threadIdx.x;
  if (bid < 6144) {
    int z = bid >> 11, x = bid & 2047;
    const float* in = z == 0 ? Q : z == 1 ? K : V;
    u16* out = z == 0 ? Xq : z == 1 ? Xk : Xv;
    int i = (x * 256 + t) * 8;
    float4 a = *(const float4*)(in + i);
    float4 b = *(const float4*)(in + i + 4);
    uint4 o;
    o.x = pack2(a.x, a.y);
    o.y = pack2(a.z, a.w);
    o.z = pack2(b.x, b.y);
    o.w = pack2(b.z, b.w);
    *(uint4*)(out + i) = o;
    return;
  }
  const float* in;
  u16* out;
  int rt, ct, R, C;
  if (bid < 6912) {
    int wid = bid - 6144;
    int z = wid >> 4;
    int mat = z >> 4, hh = z & 15;
    in = (mat == 0 ? Wq : mat == 1 ? Wk : Wv) + (size_t)hh * 1024 * 64;
    out = (mat == 0 ? WT0 : mat == 1 ? WT1 : WT2) + (size_t)hh * 1024 * 64;
    rt = wid & 15;
    ct = 0;
    R = 1024;
    C = 64;
  } else {
    int idx = bid - 6912;
    in = Wm;
    out = WT3;
    rt = idx & 15;
    ct = idx >> 4;
    R = 1024;
    C = 1024;
  }
  __shared__ float tile[64][65];
  int r = t >> 2, cc = (t & 3) * 16;
#pragma unroll
  for (int j = 0; j < 16; j += 4) {
    float4 v = *(const float4*)(in + (size_t)(rt * 64 + r) * C + ct * 64 + cc + j);
    tile[r][cc + j] = v.x;
    tile[r][cc + j + 1] = v.y;
    tile[r][cc + j + 2] = v.z;
    tile[r][cc + j + 3] = v.w;
  }
  __syncthreads();
  int c = t >> 2;
  u32 buf[8];
#pragma unroll
  for (int j = 0; j < 8; ++j)
    buf[j] = pack2(tile[cc + 2 * j][c], tile[cc + 2 * j + 1][c]);
  uint4* dst = (uint4*)(out + (size_t)(ct * 64 + c) * R + rt * 64 + cc);
  dst[0] = make_uint4(buf[0], buf[1], buf[2], buf[3]);
  dst[1] = make_uint4(buf[4], buf[5], buf[6], buf[7]);
}

// ------------- Q/K/V projection: bf16 A, gload_lds dbuf, 1 barrier/K-step -------------
__global__ __launch_bounds__(256) void proj4(
    const u16* __restrict__ Xq, const u16* __restrict__ Xk,
    const u16* __restrict__ Xv, const u16* __restrict__ WT0,
    const u16* __restrict__ WT1, const u16* __restrict__ WT2,
    const float* __restrict__ bq, const float* __restrict__ bk,
    const float* __restrict__ bv, u16* __restrict__ qp, u16* __restrict__ kp,
    u16* __restrict__ vTp) {
  int mt = blockIdx.x, nt = blockIdx.y, z = blockIdx.z;
  const u16* Ap = z == 0 ? Xq : z == 1 ? Xk : Xv;
  const u16* BT = z == 0 ? WT0 : z == 1 ? WT1 : WT2;
  const float* bias = z == 0 ? bq : z == 1 ? bk : bv;
  float scale = z == 0 ? 0.125f : 1.0f;
  int t = threadIdx.x, lane = t & 63, w = t >> 6;
  int wr = w >> 1, wc = w & 1;
  int quad = lane >> 4, col = lane & 15;
  __shared__ u16 Asm[2][128 * 64], Bsm[2][128 * 64];

#define PSTG(bi, kt)                                                            \
  {                                                                             \
    _Pragma("unroll") for (int cc_ = 0; cc_ < 4; ++cc_) {                       \
      int rb_ = w * 32 + cc_ * 8;                                               \
      stage_async(Asm[bi] + rb_ * 64,                                           \
                  Ap + (size_t)(mt * 128 + rb_) * 1024 + (kt) * 64, 1024, lane);\
      stage_async(Bsm[bi] + rb_ * 64,                                           \
                  BT + (size_t)(nt * 128 + rb_) * 1024 + (kt) * 64, 1024, lane);\
    }                                                                           \
  }

  f4 acc[4][4] = {};
  PSTG(0, 0);
  WAITVM(0);
  BAR();
  for (int kt = 0; kt < 16; ++kt) {
    int bi = kt & 1;
    if (kt < 15) PSTG(bi ^ 1, kt + 1);
#pragma unroll
    for (int kc = 0; kc < 2; ++kc) {
      bf8 a[4], b[4];
#pragma unroll
      for (int fr = 0; fr < 4; ++fr) a[fr] = ldA(Asm[bi], wr * 64 + fr * 16, kc, lane);
#pragma unroll
      for (int nf = 0; nf < 4; ++nf) b[nf] = ldA(Bsm[bi], wc * 64 + nf * 16, kc, lane);
#pragma unroll
      for (int fr = 0; fr < 4; ++fr)
#pragma unroll
        for (int nf = 0; nf < 4; ++nf)
          acc[fr][nf] = MFMA16(a[fr], b[nf], acc[fr][nf]);
    }
    if (kt < 15) {
      WAITVM(0);
      BAR();
    }
  }
#undef PSTG
  if (z < 2) {
    u16* outp = z == 0 ? qp : kp;
#pragma unroll
    for (int fr = 0; fr < 4; ++fr)
#pragma unroll
      for (int nf = 0; nf < 4; ++nf) {
        int n = nt * 128 + wc * 64 + nf * 16 + col;
        int h = n >> 6, d = n & 63;
        float bs = bias[n];
#pragma unroll
        for (int r = 0; r < 4; ++r) {
          int gm = mt * 128 + wr * 64 + fr * 16 + quad * 4 + r;
          int bb = gm >> 11, s = gm & 2047;
          outp[(size_t)((bb * H_ + h) * S_ + s) * 64 + d] =
              f2b((acc[fr][nf][r] + bs) * scale);
        }
      }
  } else {
    // V: write transposed [B*H*64][S] directly (in-lane r-run is s-contiguous)
#pragma unroll
    for (int fr = 0; fr < 4; ++fr)
#pragma unroll
      for (int nf = 0; nf < 4; ++nf) {
        int n = nt * 128 + wc * 64 + nf * 16 + col;
        int h = n >> 6, d = n & 63;
        float bs = bias[n];
        int s0 = mt * 128 + wr * 64 + fr * 16 + quad * 4;
        int bb = s0 >> 11, s = s0 & 2047;
        uint2 u;
        u.x = pack2(acc[fr][nf][0] + bs, acc[fr][nf][1] + bs);
        u.y = pack2(acc[fr][nf][2] + bs, acc[fr][nf][3] + bs);
        *(uint2*)(vTp + (size_t)((bb * H_ + h) * 64 + d) * S_ + s) = u;
      }
  }
}

// ------------- output GEMM: same pipeline, f32 row-major out -------------
__global__ __launch_bounds__(256) void gemmo2(const u16* __restrict__ A,
                                              const u16* __restrict__ BT,
                                              const float* __restrict__ bias,
                                              float* __restrict__ outp) {
  int mt = blockIdx.x, nt = blockIdx.y;
  int t = threadIdx.x, lane = t & 63, w = t >> 6;
  int wr = w >> 1, wc = w & 1;
  int quad = lane >> 4, col = lane & 15;
  __shared__ u16 Asm[2][128 * 64], Bsm[2][128 * 64];

#define PSTG(bi, kt)                                                            \
  {                                                                             \
    _Pragma("unroll") for (int cc_ = 0; cc_ < 4; ++cc_) {                       \
      int rb_ = w * 32 + cc_ * 8;                                               \
      stage_async(Asm[bi] + rb_ * 64,                                           \
                  A + (size_t)(mt * 128 + rb_) * 1024 + (kt) * 64, 1024, lane); \
      stage_async(Bsm[bi] + rb_ * 64,                                           \
                  BT + (size_t)(nt * 128 + rb_) * 1024 + (kt) * 64, 1024, lane);\
    }                                                                           \
  }

  f4 acc[4][4] = {};
  PSTG(0, 0);
  WAITVM(0);
  BAR();
  for (int kt = 0; kt < 16; ++kt) {
    int bi = kt & 1;
    if (kt < 15) PSTG(bi ^ 1, kt + 1);
#pragma unroll
    for (int kc = 0; kc < 2; ++kc) {
      bf8 a[4], b[4];
#pragma unroll
      for (int fr = 0; fr < 4; ++fr) a[fr] = ldA(Asm[bi], wr * 64 + fr * 16, kc, lane);
#pragma unroll
      for (int nf = 0; nf < 4; ++nf) b[nf] = ldA(Bsm[bi], wc * 64 + nf * 16, kc, lane);
#pragma unroll
      for (int fr = 0; fr < 4; ++fr)
#pragma unroll
        for (int nf = 0; nf < 4; ++nf)
          acc[fr][nf] = MFMA16(a[fr], b[nf], acc[fr][nf]);
    }
    if (kt < 15) {
      WAITVM(0);
      BAR();
    }
  }
#undef PSTG
#pragma unroll
  for (int fr = 0; fr < 4; ++fr)
#pragma unroll
    for (int nf = 0; nf < 4; ++nf) {
      int n = nt * 128 + wc * 64 + nf * 16 + col;
      float bs = bias[n];
#pragma unroll
      for (int r = 0; r < 4; ++r) {
        int gm = mt * 128 + wr * 64 + fr * 16 + quad * 4 + r;
        outp[(size_t)gm * 1024 + n] = acc[fr][nf][r] + bs;
      }
    }
}

// ------------- fused attention v9 -------------
// pass 1: 4-slot K ring, TWO tiles per barrier done SAFELY (unlike R9): stages
//   are issued at the TOP of the body (after the previous barrier, which proves
//   all waves finished reading the slots being overwritten), and WAITVM(0) sits
//   AFTER the 2-tile compute phase, which covers the DMA latency.
// pass 2: R8/R10 winner verbatim (1 tile/iter, vmcnt(4), barrier after compute).
__global__ void attn9(const u16* __restrict__ qp, const u16* __restrict__ kp,
                      const u16* __restrict__ vT, u16* __restrict__ ctxo,
                      float* __restrict__ attw) {
  int bid = blockIdx.x;
  int l = (bid & 7) * 128 + (bid >> 3);
  int qt = l & 31, hb = l >> 5;
  int h = hb & 15, b = hb >> 4;
  int t = threadIdx.x, lane = t & 63, w = t >> 6;
  int quad = lane >> 4, col = lane & 15;

  __shared__ u16 KV[4][64 * 64];  // pass1: 4-slot K ring; pass2: K dbuf=0,1 V dbuf=2,3
  __shared__ u16 Psm[4][16 * 64];

  const u16* kbase = kp + (size_t)(b * H_ + h) * S_ * 64;
  const u16* vbase = vT + (size_t)(b * H_ + h) * 64 * S_;
  const u16* qrow = qp + ((size_t)(b * H_ + h) * S_ + qt * 64 + w * 16) * 64;
  int r16 = (lane & 15) * 64;
  int c0 = (lane >> 4) * 8, c1 = c0 + 32;
  bf8 qf0 = g16(qrow + r16 + c0);
  bf8 qf1 = g16(qrow + r16 + c1);

#define SLOT(i) (KV[0] + (size_t)((i) & 3) * 4096)
#define SGT(slot, kt)                                                             \
  {                                                                               \
    u16* s_ = (slot);                                                             \
    const u16* g_ = kbase + (size_t)((kt) & 31) * 4096;                           \
    stage_async(s_ + w * 1024, g_ + w * 16 * 64, 64, lane);                       \
    stage_async(s_ + w * 1024 + 512, g_ + (w * 16 + 8) * 64, 64, lane);           \
  }
#define SGV(bi, kt)                                                               \
  {                                                                               \
    u16* s_ = KV[2 + (bi)];                                                       \
    stage_async(s_ + w * 1024, vbase + (size_t)(w * 16) * S_ + (kt) * 64, S_,     \
                lane);                                                            \
    stage_async(s_ + w * 1024 + 512,                                              \
                vbase + (size_t)(w * 16 + 8) * S_ + (kt) * 64, S_, lane);         \
  }

  // ---- pass 1: row sums of exp(S); 2 tiles per barrier, stage-top / wait-bottom ----
  SGT(SLOT(0), 0);
  SGT(SLOT(1), 1);
  WAITVM(0);
  BAR();
  float lsum = 0.f;
  for (int i = 0; i < 16; ++i) {
    int kt = 2 * i;
    // Overwrites slots (kt+2)&3=(kt-2)&3 and (kt+3)&3=(kt-1)&3: both were last
    // read in iter i-1, and the barrier at the bottom of iter i-1 proves every
    // wave finished that read before this DMA is issued. Wraps at i=15 to
    // pre-stage K t0,t1 into slots 0,1 for pass 2.
    SGT(SLOT(kt + 2), kt + 2);
    SGT(SLOT(kt + 3), kt + 3);
#pragma unroll
    for (int half = 0; half < 2; ++half) {
      const u16* Kc = SLOT(kt + half);
      f4 sc[4] = {};
#pragma unroll
      for (int fr = 0; fr < 4; ++fr) {
        bf8 k0 = ldA(Kc, fr * 16, 0, lane);
        bf8 k1 = ldA(Kc, fr * 16, 1, lane);
        sc[fr] = MFMA16(k0, qf0, sc[fr]);
        sc[fr] = MFMA16(k1, qf1, sc[fr]);
      }
      float s = 0.f;
#pragma unroll
      for (int fr = 0; fr < 4; ++fr)
#pragma unroll
        for (int r = 0; r < 4; ++r) s += __expf(sc[fr][r]);
      lsum += s;
    }
    // the 2-tile compute phase above covered the DMA latency; retire and publish
    WAITVM(0);
    BAR();
  }
  lsum += __shfl_xor(lsum, 16);
  lsum += __shfl_xor(lsum, 32);
  float linv = 1.f / lsum;

  // ---- pass 2: recompute S, write normalized P, accumulate ctx^T ----
  // K t0/t1 already in KV[0]/KV[1] from pass 1's wrap stages.
  SGV(0, 0);
  WAITVM(0);
  BAR();
  f4 ctxa[4] = {};
  u16* Pw = Psm[w];
  size_t awrow = ((size_t)(b * S_ + qt * 64 + w * 16) * H_ + h) * S_;
  for (int kt = 0; kt < 32; ++kt) {
    SGT(SLOT((kt + 1) & 1), kt + 1);
    SGV((kt + 1) & 1, (kt + 1) & 31);
    const u16* Kc = SLOT(kt & 1);
    const u16* Vc = KV[2 + (kt & 1)];
    f4 sc[4] = {};
#pragma unroll
    for (int fr = 0; fr < 4; ++fr) {
      bf8 k0 = ldA(Kc, fr * 16, 0, lane);
      bf8 k1 = ldA(Kc, fr * 16, 1, lane);
      sc[fr] = MFMA16(k0, qf0, sc[fr]);
      sc[fr] = MFMA16(k1, qf1, sc[fr]);
    }
    // P strip [16 q][64 key] bf16, swizzled; lane writes q=col, keys fr*16+quad*4+r
#pragma unroll
    for (int fr = 0; fr < 4; ++fr) {
      float p0 = __expf(sc[fr][0]) * linv;
      float p1 = __expf(sc[fr][1]) * linv;
      float p2 = __expf(sc[fr][2]) * linv;
      float p3 = __expf(sc[fr][3]) * linv;
      int bo = col * 128 + ((fr * 32 + quad * 8) ^ ((col & 7) << 4));
      uint2 u;
      u.x = pack2(p0, p1);
      u.y = pack2(p2, p3);
      *(uint2*)((char*)Pw + bo) = u;
    }
    // attw f32 stores (4/lane), issued early; they float across the barrier
#pragma unroll
    for (int it = 0; it < 2; ++it) {
      int row = (lane >> 3) + 8 * it;
      int cc = lane & 7;
      int bo = row * 128 + ((cc ^ (row & 7)) << 4);
      bf8 pv = *(const bf8*)((const char*)Pw + bo);
      float* dst = attw + awrow + (size_t)row * (H_ * S_) + kt * 64 + cc * 8;
      float4 o0, o1;
      o0.x = b2f((u16)pv[0]);
      o0.y = b2f((u16)pv[1]);
      o0.z = b2f((u16)pv[2]);
      o0.w = b2f((u16)pv[3]);
      o1.x = b2f((u16)pv[4]);
      o1.y = b2f((u16)pv[5]);
      o1.z = b2f((u16)pv[6]);
      o1.w = b2f((u16)pv[7]);
      *(float4*)dst = o0;
      *((float4*)dst + 1) = o1;
    }
    // PV: ctx^T[dv][q] += V^T[dv][key] * P[q][key]
    bf8 pf0 = ldA(Pw, 0, 0, lane);
    bf8 pf1 = ldA(Pw, 0, 1, lane);
#pragma unroll
    for (int fr = 0; fr < 4; ++fr) {
      bf8 v0 = ldA(Vc, fr * 16, 0, lane);
      bf8 v1 = ldA(Vc, fr * 16, 1, lane);
      ctxa[fr] = MFMA16(v0, pf0, ctxa[fr]);
      ctxa[fr] = MFMA16(v1, pf1, ctxa[fr]);
    }
    // retire prior stores + this iter's 4 stages; this iter's 4 stores float
    WAITVM(4);
    BAR();
  }
  // ctx epilogue: lane holds q=col, dv = fr*16 + quad*4 + r
  int qg = qt * 64 + w * 16 + col;
  size_t cb = ((size_t)(b * S_ + qg) * H_ + h) * 64;
#pragma unroll
  for (int fr = 0; fr < 4; ++fr) {
    uint2 u;
    u.x = pack2(ctxa[fr][0], ctxa[fr][1]);
    u.y = pack2(ctxa[fr][2], ctxa[fr][3]);
    *(uint2*)(ctxo + cb + fr * 16 + quad * 4) = u;
  }
#undef SLOT
#undef SGT
#undef SGV
}

extern "C" void kernel_launch(void* const* d_in, const int* in_sizes, int n_in,
                              void* d_out, int out_size, void* d_ws, size_t ws_size,
                              hipStream_t stream) {
  const float* Q = (const float*)d_in[0];
  const float* K = (const float*)d_in[1];
  const float* V = (const float*)d_in[2];
  const float* Wq = (const float*)d_in[3];
  const float* bq = (const float*)d_in[4];
  const float* Wk = (const float*)d_in[5];
  const float* bk = (const float*)d_in[6];
  const float* Wv = (const float*)d_in[7];
  const float* bv = (const float*)d_in[8];
  const float* Wm = (const float*)d_in[9];
  const float* bm = (const float*)d_in[10];
  float* out0 = (float*)d_out;
  float* out1 = out0 + (size_t)M_ * D_;
  (void)in_sizes; (void)n_in; (void)out_size; (void)ws_size;

  u16* WT0 = (u16*)d_ws;            // 1M elems each
  u16* WT1 = WT0 + 1048576;
  u16* WT2 = WT1 + 1048576;
  u16* WT3 = WT2 + 1048576;
  u16* qp = WT3 + 1048576;          // 4M elems each
  u16* kp = qp + 4194304;
  u16* vTp = kp + 4194304;
  u16* ctx = vTp + 4194304;         // doubles as Xq (dead before attn writes ctx)
  u16* Xk = ctx + 4194304;
  u16* Xv = Xk + 4194304;           // total 28M u16 = 56 MB

  prep<<<7168, 256, 0, stream>>>(Q, K, V, Wq, Wk, Wv, Wm, ctx, Xk, Xv, WT0, WT1,
                                 WT2, WT3);
  proj4<<<dim3(32, 8, 3), 256, 0, stream>>>(ctx, Xk, Xv, WT0, WT1, WT2, bq, bk,
                                            bv, qp, kp, vTp);
  attn9<<<1024, 256, 0, stream>>>(qp, kp, vTp, ctx, out1);
  gemmo2<<<dim3(32, 8), 256, 0, stream>>>(ctx, WT3, bm, out0);
}